// Round 1
// baseline (2137.040 us; speedup 1.0000x reference)
//
#include <hip/hip_runtime.h>

// Problem constants (from reference setup_inputs): B=128, Q=500, C=80, T=64
#define BN 128
#define QN 500
#define CLS 80
#define TN 64

typedef unsigned long long ull;

// Monotonic float->uint map: a < b  <=>  fkey(a) < fkey(b)
__device__ __forceinline__ unsigned fkey(float x) {
    unsigned u = __float_as_uint(x);
    return (u & 0x80000000u) ? ~u : (u | 0x80000000u);
}

// ---------------------------------------------------------------------------
// Kernel 1: cost matrix. One thread per (b,q,t). Wave covers t=0..63 for one q
// -> C writes coalesced 256B/wave; tgt loads coalesced; logit gather lands in
// one 320B row (L1/L2 hit); pred box / image size broadcast within the wave.
// ---------------------------------------------------------------------------
__global__ __launch_bounds__(256) void cost_kernel(
    const float* __restrict__ logits,   // [B,Q,C]
    const float* __restrict__ boxes,    // [B,Q,4]  xyxy, pixel coords
    const int*   __restrict__ ids,      // [B,T]
    const float* __restrict__ tboxes,   // [B,T,4]
    const float* __restrict__ img,      // [B,4]
    float* __restrict__ Cout)           // [B,Q,T]
{
    int idx = blockIdx.x * 256 + threadIdx.x;
    int t  = idx & 63;
    int qq = idx >> 6;
    int q  = qq % QN;
    int b  = qq / QN;

    const float4 pb = *(const float4*)(boxes  + (size_t)(b * QN + q) * 4);
    const float4 tb = *(const float4*)(tboxes + (size_t)(b * TN + t) * 4);
    const float4 im = *(const float4*)(img + b * 4);
    int   id = ids[b * TN + t];
    float x  = logits[(size_t)(b * QN + q) * CLS + id];

    // focal-style class cost (matches reference op order)
    float prob = 1.0f / (1.0f + expf(-x));
    float neg  = 0.75f * (prob * prob) * (-log1pf(1e-8f - prob));
    float pos  = 0.25f * ((1.0f - prob) * (1.0f - prob)) * (-logf(prob + 1e-8f));
    float cls  = pos - neg;

    // L1 on normalized boxes (normalize each side separately, like reference)
    float l1 = fabsf(pb.x / im.x - tb.x / im.x)
             + fabsf(pb.y / im.y - tb.y / im.y)
             + fabsf(pb.z / im.z - tb.z / im.z)
             + fabsf(pb.w / im.w - tb.w / im.w);

    // GIoU on pixel boxes
    float area_a = (pb.z - pb.x) * (pb.w - pb.y);
    float area_b = (tb.z - tb.x) * (tb.w - tb.y);
    float ltx = fmaxf(pb.x, tb.x), lty = fmaxf(pb.y, tb.y);
    float rbx = fminf(pb.z, tb.z), rby = fminf(pb.w, tb.w);
    float iw = fmaxf(rbx - ltx, 0.0f), ih = fmaxf(rby - lty, 0.0f);
    float inter = iw * ih;
    float uni   = area_a + area_b - inter;
    float iou   = inter / uni;
    float ex1 = fminf(pb.x, tb.x), ey1 = fminf(pb.y, tb.y);
    float ex2 = fmaxf(pb.z, tb.z), ey2 = fmaxf(pb.w, tb.w);
    float ew = fmaxf(ex2 - ex1, 0.0f), eh = fmaxf(ey2 - ey1, 0.0f);
    float enc = ew * eh;
    float giou = iou - (enc - uni) / enc;

    Cout[idx] = 5.0f * l1 + 2.0f * cls + 2.0f * (-giou);
}

// ---------------------------------------------------------------------------
// Kernel 2: greedy assignment. One 64-lane wave per image. Row minima kept as
// packed u64 keys (sortable_bits<<32 | flat_idx) so u64-min == reference's
// argmin-with-first-occurrence-tie-break over the raveled masked matrix.
// Lane L owns rows {L, L+64, ..., L+448}; keys live in registers; reduce via
// shuffle butterfly -> no __syncthreads in the hot loop.
// ---------------------------------------------------------------------------
__global__ __launch_bounds__(64) void assign_kernel(
    const float* __restrict__ Cmat,     // [B,Q,T]
    float* __restrict__ out_rows,       // [B,T] (as f32 values)
    float* __restrict__ out_cols)       // [B,T]
{
    int b    = blockIdx.x;
    int lane = threadIdx.x;
    const float* Cb = Cmat + (size_t)b * QN * TN;

    __shared__ ull rowkey_lds[QN];      // init staging only

    // ---- init: cooperative row minima. 8 rows per tile; lane (rsub,csub)
    // reads 8 consecutive floats -> a tile load is fully contiguous 2KB.
    int rsub = lane >> 3;               // row within tile
    int csub = (lane & 7) << 3;         // col start (8 cols per lane)
    for (int i0 = 0; i0 < QN; i0 += 8) {
        int r = i0 + rsub;
        ull key = ~0ull;
        if (r < QN) {
            const float4* rp = (const float4*)(Cb + r * 64 + csub);
            float4 a = rp[0], c4 = rp[1];
            float vv[8] = {a.x, a.y, a.z, a.w, c4.x, c4.y, c4.z, c4.w};
            #pragma unroll
            for (int c = 0; c < 8; ++c) {
                ull k = ((ull)fkey(vv[c]) << 32) | (unsigned)(r * 64 + csub + c);
                if (k < key) key = k;
            }
        }
        #pragma unroll
        for (int off = 1; off < 8; off <<= 1) {   // reduce among the 8 lanes of a row
            ull o = __shfl_xor(key, off);
            if (o < key) key = o;
        }
        if ((lane & 7) == 0 && r < QN) rowkey_lds[r] = key;
    }
    __syncthreads();

    // pull my rows' keys into registers
    ull key[8];
    #pragma unroll
    for (int k = 0; k < 8; ++k) {
        int r = lane + (k << 6);
        key[k] = (r < QN) ? rowkey_lds[r] : ~0ull;
    }

    ull colmask = 0;                    // retired columns (replicated per lane)
    for (int t = 0; t < TN; ++t) {
        // global min = min over all row keys (exactly ref's masked argmin)
        ull best = key[0];
        #pragma unroll
        for (int k = 1; k < 8; ++k) if (key[k] < best) best = key[k];
        #pragma unroll
        for (int off = 1; off < 64; off <<= 1) {
            ull o = __shfl_xor(best, off);
            if (o < best) best = o;
        }
        unsigned flat = (unsigned)best;  // = i*64 + j
        int i = (int)(flat >> 6);
        int j = (int)(flat & 63u);
        if (lane == 0) {
            out_rows[b * TN + t] = (float)i;
            out_cols[b * TN + t] = (float)j;
        }
        colmask |= (1ull << j);

        // retire row i (owner lane only; static unroll avoids scratch)
        if ((i & 63) == lane) {
            int ki = i >> 6;
            #pragma unroll
            for (int k = 0; k < 8; ++k) if (k == ki) key[k] = ~0ull;
        }

        // rows whose arg-col was j must rescan remaining cols
        #pragma unroll
        for (int k = 0; k < 8; ++k) {
            int r = lane + (k << 6);
            bool need = (r < QN) && (key[k] != ~0ull) &&
                        ((unsigned)(key[k] & 63u) == (unsigned)j);
            if (need) {
                const float* rp = Cb + r * 64;
                ull nb = ~0ull;
                for (int c = 0; c < 64; ++c) {
                    if (!((colmask >> c) & 1ull)) {
                        ull kk = ((ull)fkey(rp[c]) << 32) | (unsigned)(r * 64 + c);
                        if (kk < nb) nb = kk;
                    }
                }
                key[k] = nb;
            }
        }
    }
}

extern "C" void kernel_launch(void* const* d_in, const int* in_sizes, int n_in,
                              void* d_out, int out_size, void* d_ws, size_t ws_size,
                              hipStream_t stream) {
    const float* logits = (const float*)d_in[0];   // [128,500,80]
    const float* boxes  = (const float*)d_in[1];   // [128,500,4]
    const int*   ids    = (const int*)d_in[2];     // [128,64]
    const float* tboxes = (const float*)d_in[3];   // [128,64,4]
    const float* img    = (const float*)d_in[4];   // [128,4]

    float* out  = (float*)d_out;
    float* Cmat = out;                              // 128*500*64 = 4,096,000
    float* rows = out + (size_t)BN * QN * TN;       // +8192
    float* cols = rows + BN * TN;                   // +8192

    int total = BN * QN * TN;                       // 4,096,000 (divisible by 256)
    cost_kernel<<<total / 256, 256, 0, stream>>>(logits, boxes, ids, tboxes, img, Cmat);
    assign_kernel<<<BN, 64, 0, stream>>>(Cmat, rows, cols);
}

// Round 2
// 344.026 us; speedup vs baseline: 6.2118x; 6.2118x over previous
//
#include <hip/hip_runtime.h>

// Problem constants (from reference setup_inputs): B=128, Q=500, C=80, T=64
#define BN 128
#define QN 500
#define CLS 80
#define TN 64

typedef unsigned long long ull;

// Monotonic float->uint map: a < b  <=>  fkey(a) < fkey(b)
__device__ __forceinline__ unsigned fkey(float x) {
    unsigned u = __float_as_uint(x);
    return (u & 0x80000000u) ? ~u : (u | 0x80000000u);
}

// ---------------------------------------------------------------------------
// Kernel 1: cost matrix. One thread per (b,q,t). Wave covers t=0..63 for one q
// -> C writes coalesced 256B/wave; tgt loads coalesced; logit gather lands in
// one 320B row (L1/L2 hit); pred box / image size broadcast within the wave.
// ---------------------------------------------------------------------------
__global__ __launch_bounds__(256) void cost_kernel(
    const float* __restrict__ logits,   // [B,Q,C]
    const float* __restrict__ boxes,    // [B,Q,4]  xyxy, pixel coords
    const int*   __restrict__ ids,      // [B,T]
    const float* __restrict__ tboxes,   // [B,T,4]
    const float* __restrict__ img,      // [B,4]
    float* __restrict__ Cout)           // [B,Q,T]
{
    int idx = blockIdx.x * 256 + threadIdx.x;
    int t  = idx & 63;
    int qq = idx >> 6;
    int q  = qq % QN;
    int b  = qq / QN;

    const float4 pb = *(const float4*)(boxes  + (size_t)(b * QN + q) * 4);
    const float4 tb = *(const float4*)(tboxes + (size_t)(b * TN + t) * 4);
    const float4 im = *(const float4*)(img + b * 4);
    int   id = ids[b * TN + t];
    float x  = logits[(size_t)(b * QN + q) * CLS + id];

    // focal-style class cost (matches reference op order)
    float prob = 1.0f / (1.0f + expf(-x));
    float neg  = 0.75f * (prob * prob) * (-log1pf(1e-8f - prob));
    float pos  = 0.25f * ((1.0f - prob) * (1.0f - prob)) * (-logf(prob + 1e-8f));
    float cls  = pos - neg;

    // L1 on normalized boxes (normalize each side separately, like reference)
    float l1 = fabsf(pb.x / im.x - tb.x / im.x)
             + fabsf(pb.y / im.y - tb.y / im.y)
             + fabsf(pb.z / im.z - tb.z / im.z)
             + fabsf(pb.w / im.w - tb.w / im.w);

    // GIoU on pixel boxes
    float area_a = (pb.z - pb.x) * (pb.w - pb.y);
    float area_b = (tb.z - tb.x) * (tb.w - tb.y);
    float ltx = fmaxf(pb.x, tb.x), lty = fmaxf(pb.y, tb.y);
    float rbx = fminf(pb.z, tb.z), rby = fminf(pb.w, tb.w);
    float iw = fmaxf(rbx - ltx, 0.0f), ih = fmaxf(rby - lty, 0.0f);
    float inter = iw * ih;
    float uni   = area_a + area_b - inter;
    float iou   = inter / uni;
    float ex1 = fminf(pb.x, tb.x), ey1 = fminf(pb.y, tb.y);
    float ex2 = fmaxf(pb.z, tb.z), ey2 = fmaxf(pb.w, tb.w);
    float ew = fmaxf(ex2 - ex1, 0.0f), eh = fmaxf(ey2 - ey1, 0.0f);
    float enc = ew * eh;
    float giou = iou - (enc - uni) / enc;

    Cout[idx] = 5.0f * l1 + 2.0f * cls + 2.0f * (-giou);
}

// ---------------------------------------------------------------------------
// Kernel 2: greedy assignment, register-resident.
// One block (256 threads = 4 waves) per image. Thread tid owns rows tid and
// tid+256; the full 500x64 matrix lives in VGPRs (128 floats/thread). Row
// minima as packed u64 keys (fkey<<32 | flat_idx): u64-min == reference's
// raveled argmin incl. first-occurrence tie-break. Hot loop is pure VALU +
// shuffles + a 4-slot LDS cross-wave reduce -- no global memory at all.
// ---------------------------------------------------------------------------
__global__ __launch_bounds__(256, 1) void assign_kernel(
    const float* __restrict__ Cmat,     // [B,Q,T]
    float* __restrict__ out_rows,       // [B,T] (as f32 values)
    float* __restrict__ out_cols)       // [B,T]
{
    const int b   = blockIdx.x;
    const int tid = threadIdx.x;
    const float* Cb = Cmat + (size_t)b * QN * TN;

    const int r0 = tid;                 // always < 500
    const int r1 = tid + 256;
    const bool has1 = (r1 < QN);

    // ---- load owned rows into registers (float4 x 16 per row, all issued
    // before use -> single waitcnt, L2-resident from cost_kernel)
    float row0[TN];
    float row1[TN];
    {
        const float4* p0 = (const float4*)(Cb + (size_t)r0 * TN);
        #pragma unroll
        for (int c4 = 0; c4 < TN / 4; ++c4) {
            float4 v = p0[c4];
            row0[c4 * 4 + 0] = v.x; row0[c4 * 4 + 1] = v.y;
            row0[c4 * 4 + 2] = v.z; row0[c4 * 4 + 3] = v.w;
        }
        if (has1) {
            const float4* p1 = (const float4*)(Cb + (size_t)r1 * TN);
            #pragma unroll
            for (int c4 = 0; c4 < TN / 4; ++c4) {
                float4 v = p1[c4];
                row1[c4 * 4 + 0] = v.x; row1[c4 * 4 + 1] = v.y;
                row1[c4 * 4 + 2] = v.z; row1[c4 * 4 + 3] = v.w;
            }
        } else {
            #pragma unroll
            for (int c = 0; c < TN; ++c) row1[c] = __uint_as_float(0x7f800000u); // +inf
        }
    }

    // ---- initial per-row min keys
    ull key0 = ~0ull, key1 = ~0ull;
    #pragma unroll
    for (int c = 0; c < TN; ++c) {
        ull k = ((ull)fkey(row0[c]) << 32) | (unsigned)(r0 * TN + c);
        if (k < key0) key0 = k;
    }
    if (has1) {
        #pragma unroll
        for (int c = 0; c < TN; ++c) {
            ull k = ((ull)fkey(row1[c]) << 32) | (unsigned)(r1 * TN + c);
            if (k < key1) key1 = k;
        }
    }

    __shared__ ull wavemin[4];
    ull colmask = 0;

    for (int t = 0; t < TN; ++t) {
        // thread-local then wave-level min
        ull best = (key1 < key0) ? key1 : key0;
        #pragma unroll
        for (int off = 1; off < 64; off <<= 1) {
            ull o = __shfl_xor(best, off);
            if (o < best) best = o;
        }
        if ((tid & 63) == 0) wavemin[tid >> 6] = best;
        __syncthreads();
        // cross-wave min (each thread reads all 4 slots)
        best = wavemin[0];
        {
            ull o = wavemin[1]; if (o < best) best = o;
            o = wavemin[2]; if (o < best) best = o;
            o = wavemin[3]; if (o < best) best = o;
        }
        __syncthreads();   // protect wavemin slots before next iteration's write

        unsigned flat = (unsigned)best;          // = i*64 + j
        int i = (int)(flat >> 6);
        int j = (int)(flat & 63u);
        if (tid == 0) {
            out_rows[b * TN + t] = (float)i;
            out_cols[b * TN + t] = (float)j;
        }
        colmask |= (1ull << j);

        // retire winning row (key==~0 marks retired/invalid)
        if (i == r0) key0 = ~0ull;
        if (has1 && i == r1) key1 = ~0ull;

        // rows whose current arg-col just got retired: recompute masked min
        // from REGISTERS (pure VALU, fully unrolled, no memory)
        if (key0 != ~0ull && (unsigned)(key0 & 63u) == (unsigned)j) {
            ull nb = ~0ull;
            #pragma unroll
            for (int c = 0; c < TN; ++c) {
                if (!((colmask >> c) & 1ull)) {
                    ull k = ((ull)fkey(row0[c]) << 32) | (unsigned)(r0 * TN + c);
                    if (k < nb) nb = k;
                }
            }
            key0 = nb;
        }
        if (key1 != ~0ull && (unsigned)(key1 & 63u) == (unsigned)j) {
            ull nb = ~0ull;
            #pragma unroll
            for (int c = 0; c < TN; ++c) {
                if (!((colmask >> c) & 1ull)) {
                    ull k = ((ull)fkey(row1[c]) << 32) | (unsigned)(r1 * TN + c);
                    if (k < nb) nb = k;
                }
            }
            key1 = nb;
        }
    }
}

extern "C" void kernel_launch(void* const* d_in, const int* in_sizes, int n_in,
                              void* d_out, int out_size, void* d_ws, size_t ws_size,
                              hipStream_t stream) {
    const float* logits = (const float*)d_in[0];   // [128,500,80]
    const float* boxes  = (const float*)d_in[1];   // [128,500,4]
    const int*   ids    = (const int*)d_in[2];     // [128,64]
    const float* tboxes = (const float*)d_in[3];   // [128,64,4]
    const float* img    = (const float*)d_in[4];   // [128,4]

    float* out  = (float*)d_out;
    float* Cmat = out;                              // 128*500*64 = 4,096,000
    float* rows = out + (size_t)BN * QN * TN;       // +8192
    float* cols = rows + BN * TN;                   // +8192

    int total = BN * QN * TN;                       // 4,096,000 (divisible by 256)
    cost_kernel<<<total / 256, 256, 0, stream>>>(logits, boxes, ids, tboxes, img, Cmat);
    assign_kernel<<<BN, 256, 0, stream>>>(Cmat, rows, cols);
}

// Round 3
// 335.691 us; speedup vs baseline: 6.3661x; 1.0248x over previous
//
#include <hip/hip_runtime.h>

// Problem constants (from reference setup_inputs): B=128, Q=500, C=80, T=64
#define BN 128
#define QN 500
#define CLS 80
#define TN 64

typedef unsigned long long ull;

// Monotonic float->uint map: a < b  <=>  fkey(a) < fkey(b)
__device__ __forceinline__ unsigned fkey(float x) {
    unsigned u = __float_as_uint(x);
    return (u & 0x80000000u) ? ~u : (u | 0x80000000u);
}

// ---------------------------------------------------------------------------
// Kernel 1: cost matrix. One thread per (b,q,t). Wave covers t=0..63 for one q
// -> C writes coalesced 256B/wave; tgt loads coalesced; logit gather lands in
// one 320B row (L1/L2 hit); pred box / image size broadcast within the wave.
// ---------------------------------------------------------------------------
__global__ __launch_bounds__(256) void cost_kernel(
    const float* __restrict__ logits,   // [B,Q,C]
    const float* __restrict__ boxes,    // [B,Q,4]  xyxy, pixel coords
    const int*   __restrict__ ids,      // [B,T]
    const float* __restrict__ tboxes,   // [B,T,4]
    const float* __restrict__ img,      // [B,4]
    float* __restrict__ Cout)           // [B,Q,T]
{
    int idx = blockIdx.x * 256 + threadIdx.x;
    int t  = idx & 63;
    int qq = idx >> 6;
    int q  = qq % QN;
    int b  = qq / QN;

    const float4 pb = *(const float4*)(boxes  + (size_t)(b * QN + q) * 4);
    const float4 tb = *(const float4*)(tboxes + (size_t)(b * TN + t) * 4);
    const float4 im = *(const float4*)(img + b * 4);
    int   id = ids[b * TN + t];
    float x  = logits[(size_t)(b * QN + q) * CLS + id];

    // focal-style class cost (matches reference op order)
    float prob = 1.0f / (1.0f + expf(-x));
    float neg  = 0.75f * (prob * prob) * (-log1pf(1e-8f - prob));
    float pos  = 0.25f * ((1.0f - prob) * (1.0f - prob)) * (-logf(prob + 1e-8f));
    float cls  = pos - neg;

    // L1 on normalized boxes (normalize each side separately, like reference)
    float l1 = fabsf(pb.x / im.x - tb.x / im.x)
             + fabsf(pb.y / im.y - tb.y / im.y)
             + fabsf(pb.z / im.z - tb.z / im.z)
             + fabsf(pb.w / im.w - tb.w / im.w);

    // GIoU on pixel boxes
    float area_a = (pb.z - pb.x) * (pb.w - pb.y);
    float area_b = (tb.z - tb.x) * (tb.w - tb.y);
    float ltx = fmaxf(pb.x, tb.x), lty = fmaxf(pb.y, tb.y);
    float rbx = fminf(pb.z, tb.z), rby = fminf(pb.w, tb.w);
    float iw = fmaxf(rbx - ltx, 0.0f), ih = fmaxf(rby - lty, 0.0f);
    float inter = iw * ih;
    float uni   = area_a + area_b - inter;
    float iou   = inter / uni;
    float ex1 = fminf(pb.x, tb.x), ey1 = fminf(pb.y, tb.y);
    float ex2 = fmaxf(pb.z, tb.z), ey2 = fmaxf(pb.w, tb.w);
    float ew = fmaxf(ex2 - ex1, 0.0f), eh = fmaxf(ey2 - ey1, 0.0f);
    float enc = ew * eh;
    float giou = iou - (enc - uni) / enc;

    Cout[idx] = 5.0f * l1 + 2.0f * cls + 2.0f * (-giou);
}

// ---------------------------------------------------------------------------
// Kernel 2: greedy assignment, register-resident PRE-PACKED u64 keys.
// One block (256 threads) per image; thread owns rows tid and tid+256.
// key[c] = (fkey(cost)<<32) | (row*64+c)  -- u64-min over keys == reference's
// raveled argmin incl. first-occurrence tie-break.
// Hot-loop design vs round 2:
//  * keys pre-packed at init -> rescan col step = cmp_lt_u64 + 2 cndmask
//  * i/j/colmask made wave-uniform via readfirstlane -> colmask lives in
//    SGPRs; per-column retired test is a scalar branch that SKIPS the min
//  * ping-pong wavemin slots -> ONE __syncthreads per iteration
// ---------------------------------------------------------------------------
__global__ __launch_bounds__(256, 1) void assign_kernel(
    const float* __restrict__ Cmat,     // [B,Q,T]
    float* __restrict__ out_rows,       // [B,T] (as f32 values)
    float* __restrict__ out_cols)       // [B,T]
{
    const int b   = blockIdx.x;
    const int tid = threadIdx.x;
    const float* Cb = Cmat + (size_t)b * QN * TN;

    const int r0 = tid;                 // always < 500
    const int r1 = tid + 256;
    const bool has1 = (r1 < QN);

    // ---- init: load rows, pack keys immediately (keeps live set small)
    ull k0[TN], k1[TN];
    {
        const float4* p0 = (const float4*)(Cb + (size_t)r0 * TN);
        #pragma unroll
        for (int c4 = 0; c4 < TN / 4; ++c4) {
            float4 v = p0[c4];
            int c = c4 * 4;
            k0[c + 0] = ((ull)fkey(v.x) << 32) | (unsigned)(r0 * TN + c + 0);
            k0[c + 1] = ((ull)fkey(v.y) << 32) | (unsigned)(r0 * TN + c + 1);
            k0[c + 2] = ((ull)fkey(v.z) << 32) | (unsigned)(r0 * TN + c + 2);
            k0[c + 3] = ((ull)fkey(v.w) << 32) | (unsigned)(r0 * TN + c + 3);
        }
        if (has1) {
            const float4* p1 = (const float4*)(Cb + (size_t)r1 * TN);
            #pragma unroll
            for (int c4 = 0; c4 < TN / 4; ++c4) {
                float4 v = p1[c4];
                int c = c4 * 4;
                k1[c + 0] = ((ull)fkey(v.x) << 32) | (unsigned)(r1 * TN + c + 0);
                k1[c + 1] = ((ull)fkey(v.y) << 32) | (unsigned)(r1 * TN + c + 1);
                k1[c + 2] = ((ull)fkey(v.z) << 32) | (unsigned)(r1 * TN + c + 2);
                k1[c + 3] = ((ull)fkey(v.w) << 32) | (unsigned)(r1 * TN + c + 3);
            }
        } else {
            #pragma unroll
            for (int c = 0; c < TN; ++c) k1[c] = ~0ull;
        }
    }

    // ---- initial per-row min keys
    ull m0 = k0[0], m1 = k1[0];
    #pragma unroll
    for (int c = 1; c < TN; ++c) { if (k0[c] < m0) m0 = k0[c]; }
    #pragma unroll
    for (int c = 1; c < TN; ++c) { if (k1[c] < m1) m1 = k1[c]; }

    __shared__ ull wavemin[8];          // ping-pong: 4 slots per parity
    ull colmask = 0;                    // wave-uniform (j is readfirstlane'd)

    for (int t = 0; t < TN; ++t) {
        // thread-local then wave-level min
        ull best = (m1 < m0) ? m1 : m0;
        #pragma unroll
        for (int off = 1; off < 64; off <<= 1) {
            ull o = __shfl_xor(best, off);
            if (o < best) best = o;
        }
        const int base = (t & 1) * 4;
        if ((tid & 63) == 0) wavemin[base + (tid >> 6)] = best;
        __syncthreads();                // single barrier (ping-pong => no WAR)
        best = wavemin[base + 0];
        { ull o = wavemin[base + 1]; if (o < best) best = o;
          o = wavemin[base + 2]; if (o < best) best = o;
          o = wavemin[base + 3]; if (o < best) best = o; }

        unsigned flat = __builtin_amdgcn_readfirstlane((unsigned)best);
        int i = (int)(flat >> 6);       // scalar
        int j = (int)(flat & 63u);      // scalar
        if (tid == 0) {
            out_rows[b * TN + t] = (float)i;
            out_cols[b * TN + t] = (float)j;
        }
        colmask |= (1ull << j);         // scalar arithmetic

        // retire winning row
        if (i == r0) m0 = ~0ull;
        if (i == r1) m1 = ~0ull;

        // rows whose current arg-col just got retired: recompute masked min.
        // colmask tests are wave-uniform -> scalar branch skips retired cols.
        if (m0 != ~0ull && (unsigned)(m0 & 63u) == (unsigned)j) {
            ull nb = ~0ull;
            #pragma unroll
            for (int c = 0; c < TN; ++c) {
                if (!((colmask >> c) & 1ull)) {
                    if (k0[c] < nb) nb = k0[c];
                }
            }
            m0 = nb;
        }
        if (m1 != ~0ull && (unsigned)(m1 & 63u) == (unsigned)j) {
            ull nb = ~0ull;
            #pragma unroll
            for (int c = 0; c < TN; ++c) {
                if (!((colmask >> c) & 1ull)) {
                    if (k1[c] < nb) nb = k1[c];
                }
            }
            m1 = nb;
        }
    }
}

extern "C" void kernel_launch(void* const* d_in, const int* in_sizes, int n_in,
                              void* d_out, int out_size, void* d_ws, size_t ws_size,
                              hipStream_t stream) {
    const float* logits = (const float*)d_in[0];   // [128,500,80]
    const float* boxes  = (const float*)d_in[1];   // [128,500,4]
    const int*   ids    = (const int*)d_in[2];     // [128,64]
    const float* tboxes = (const float*)d_in[3];   // [128,64,4]
    const float* img    = (const float*)d_in[4];   // [128,4]

    float* out  = (float*)d_out;
    float* Cmat = out;                              // 128*500*64 = 4,096,000
    float* rows = out + (size_t)BN * QN * TN;       // +8192
    float* cols = rows + BN * TN;                   // +8192

    int total = BN * QN * TN;                       // 4,096,000 (divisible by 256)
    cost_kernel<<<total / 256, 256, 0, stream>>>(logits, boxes, ids, tboxes, img, Cmat);
    assign_kernel<<<BN, 256, 0, stream>>>(Cmat, rows, cols);
}

// Round 4
// 173.796 us; speedup vs baseline: 12.2962x; 1.9315x over previous
//
#include <hip/hip_runtime.h>

// Problem constants (from reference setup_inputs): B=128, Q=500, C=80, T=64
#define BN 128
#define QN 500
#define CLS 80
#define TN 64

typedef unsigned long long ull;

// Monotonic float->uint map: a < b  <=>  fkey(a) < fkey(b); a==b <=> equal keys
__device__ __forceinline__ unsigned fkey(float x) {
    unsigned u = __float_as_uint(x);
    return (u & 0x80000000u) ? ~u : (u | 0x80000000u);
}

// ---------------------------------------------------------------------------
// Kernel 1: cost matrix. One thread per (b,q,t). Wave covers t=0..63 for one q
// -> C writes coalesced 256B/wave; tgt loads coalesced; logit gather lands in
// one 320B row (L1/L2 hit); pred box / image size broadcast within the wave.
// ---------------------------------------------------------------------------
__global__ __launch_bounds__(256) void cost_kernel(
    const float* __restrict__ logits,   // [B,Q,C]
    const float* __restrict__ boxes,    // [B,Q,4]  xyxy, pixel coords
    const int*   __restrict__ ids,      // [B,T]
    const float* __restrict__ tboxes,   // [B,T,4]
    const float* __restrict__ img,      // [B,4]
    float* __restrict__ Cout)           // [B,Q,T]
{
    int idx = blockIdx.x * 256 + threadIdx.x;
    int t  = idx & 63;
    int qq = idx >> 6;
    int q  = qq % QN;
    int b  = qq / QN;

    const float4 pb = *(const float4*)(boxes  + (size_t)(b * QN + q) * 4);
    const float4 tb = *(const float4*)(tboxes + (size_t)(b * TN + t) * 4);
    const float4 im = *(const float4*)(img + b * 4);
    int   id = ids[b * TN + t];
    float x  = logits[(size_t)(b * QN + q) * CLS + id];

    // focal-style class cost (matches reference op order)
    float prob = 1.0f / (1.0f + expf(-x));
    float neg  = 0.75f * (prob * prob) * (-log1pf(1e-8f - prob));
    float pos  = 0.25f * ((1.0f - prob) * (1.0f - prob)) * (-logf(prob + 1e-8f));
    float cls  = pos - neg;

    // L1 on normalized boxes (normalize each side separately, like reference)
    float l1 = fabsf(pb.x / im.x - tb.x / im.x)
             + fabsf(pb.y / im.y - tb.y / im.y)
             + fabsf(pb.z / im.z - tb.z / im.z)
             + fabsf(pb.w / im.w - tb.w / im.w);

    // GIoU on pixel boxes
    float area_a = (pb.z - pb.x) * (pb.w - pb.y);
    float area_b = (tb.z - tb.x) * (tb.w - tb.y);
    float ltx = fmaxf(pb.x, tb.x), lty = fmaxf(pb.y, tb.y);
    float rbx = fminf(pb.z, tb.z), rby = fminf(pb.w, tb.w);
    float iw = fmaxf(rbx - ltx, 0.0f), ih = fmaxf(rby - lty, 0.0f);
    float inter = iw * ih;
    float uni   = area_a + area_b - inter;
    float iou   = inter / uni;
    float ex1 = fminf(pb.x, tb.x), ey1 = fminf(pb.y, tb.y);
    float ex2 = fmaxf(pb.z, tb.z), ey2 = fmaxf(pb.w, tb.w);
    float ew = fmaxf(ex2 - ex1, 0.0f), eh = fmaxf(ey2 - ey1, 0.0f);
    float enc = ew * eh;
    float giou = iou - (enc - uni) / enc;

    Cout[idx] = 5.0f * l1 + 2.0f * cls + 2.0f * (-giou);
}

// ---------------------------------------------------------------------------
// Kernel 2: greedy assignment, COLUMN-state formulation.
// colmin[j] = lexicographic min over alive rows of key(r,j)=(fkey<<32 | r*64+j)
// held in lane j's registers of wave 0. Global u64-min over lanes == exact
// reference raveled argmin (value-min, then smallest flat index).
// Retire col j_win: lane j_win sets INF. Retire row i: uniform 512-bit dead
// mask (8 u64 regs, statically indexed). Columns whose stored argmin row == i
// (expected ~4.4 TOTAL per image) rescan cooperatively: 64 lanes x 8 strided
// loads + butterfly. Hot loop: single wave, NO barriers, NO LDS.
// Init: 8 waves, lane c scans column c over a row-strip -> 256B coalesced
// loads; per-wave colmins merge through 4KB LDS; waves 1..7 exit.
// ---------------------------------------------------------------------------
__global__ __launch_bounds__(512, 1) void assign_kernel(
    const float* __restrict__ Cmat,     // [B,Q,T]
    float* __restrict__ out_rows,       // [B,T] (as f32 values)
    float* __restrict__ out_cols)       // [B,T]
{
    const int b    = blockIdx.x;
    const int tid  = threadIdx.x;
    const int wave = tid >> 6;
    const int lane = tid & 63;
    const float* Cb = Cmat + (size_t)b * QN * TN;

    __shared__ ull wavecol[8][TN];

    // ---- init: wave w scans rows [w*63, ...); lane c owns column c.
    // Each load instruction: 64 lanes read one 256B row -> fully coalesced.
    {
        int rbeg = wave * 63;
        int rend = (wave == 7) ? QN : rbeg + 63;   // waves 0..6: 63 rows, wave 7: 59
        ull k = ~0ull;
        for (int r = rbeg; r < rend; ++r) {
            float v = Cb[(size_t)r * TN + lane];
            ull kk = ((ull)fkey(v) << 32) | (unsigned)(r * TN + lane);
            if (kk < k) k = kk;
        }
        wavecol[wave][lane] = k;
    }
    __syncthreads();
    if (wave != 0) return;                         // hot loop is single-wave

    // final per-column min (lane = column)
    ull mykey = wavecol[0][lane];
    #pragma unroll
    for (int w = 1; w < 8; ++w) {
        ull o = wavecol[w][lane];
        if (o < mykey) mykey = o;
    }

    // row-dead bitmask, wave-uniform, statically indexed registers.
    // rows 500..511 (rescan over-range) pre-marked dead.
    ull rowdead[8];
    #pragma unroll
    for (int w = 0; w < 8; ++w) rowdead[w] = 0ull;
    rowdead[7] = 0xFFF0000000000000ull;

    for (int t = 0; t < TN; ++t) {
        // global argmin: butterfly over 64 column keys
        ull best = mykey;
        #pragma unroll
        for (int off = 1; off < 64; off <<= 1) {
            ull o = __shfl_xor(best, off);
            if (o < best) best = o;
        }
        unsigned flat = (unsigned)best;            // = i*64 + j
        int i = (int)(flat >> 6);
        int j = (int)(flat & 63u);
        if (lane == 0) {
            out_rows[b * TN + t] = (float)i;
            out_cols[b * TN + t] = (float)j;
        }

        // retire winning column
        if (lane == j) mykey = ~0ull;
        // retire winning row (uniform update, static indices)
        #pragma unroll
        for (int w = 0; w < 8; ++w)
            if ((i >> 6) == w) rowdead[w] |= (1ull << (i & 63));

        // columns whose stored argmin row just died must rescan.
        // INF keys have flat=0xFFFFFFFF -> argrow 0x3FFFFFF != i, auto-excluded.
        unsigned argrow = ((unsigned)mykey) >> 6;
        ull need = __ballot(argrow == (unsigned)i);
        while (need) {
            int src = __ffsll(need) - 1;
            need &= need - 1;
            unsigned jr = __shfl((unsigned)mykey, src) & 63u;
            // cooperative rescan of column jr: lane covers rows lane+64k.
            // Loads may touch rows 500..511 (still inside d_out buffer:
            // max idx 127*32000+511*64+63 = 4,096,767 < 4,112,384) and are
            // masked dead. Ascending-row strict < keeps smallest flat on ties.
            ull nb = ~0ull;
            #pragma unroll
            for (int k8 = 0; k8 < 8; ++k8) {
                int r = lane + (k8 << 6);
                float v = Cb[(size_t)r * TN + (int)jr];
                bool dead = (rowdead[k8] >> lane) & 1ull;
                ull kk = dead ? ~0ull
                              : (((ull)fkey(v) << 32) | (unsigned)(r * TN + (int)jr));
                if (kk < nb) nb = kk;
            }
            #pragma unroll
            for (int off = 1; off < 64; off <<= 1) {
                ull o = __shfl_xor(nb, off);
                if (o < nb) nb = o;
            }
            if (lane == (int)jr) mykey = nb;
        }
    }
}

extern "C" void kernel_launch(void* const* d_in, const int* in_sizes, int n_in,
                              void* d_out, int out_size, void* d_ws, size_t ws_size,
                              hipStream_t stream) {
    const float* logits = (const float*)d_in[0];   // [128,500,80]
    const float* boxes  = (const float*)d_in[1];   // [128,500,4]
    const int*   ids    = (const int*)d_in[2];     // [128,64]
    const float* tboxes = (const float*)d_in[3];   // [128,64,4]
    const float* img    = (const float*)d_in[4];   // [128,4]

    float* out  = (float*)d_out;
    float* Cmat = out;                              // 128*500*64 = 4,096,000
    float* rows = out + (size_t)BN * QN * TN;       // +8192
    float* cols = rows + BN * TN;                   // +8192

    int total = BN * QN * TN;                       // 4,096,000 (divisible by 256)
    cost_kernel<<<total / 256, 256, 0, stream>>>(logits, boxes, ids, tboxes, img, Cmat);
    assign_kernel<<<BN, 512, 0, stream>>>(Cmat, rows, cols);
}

// Round 6
// 154.285 us; speedup vs baseline: 13.8513x; 1.1265x over previous
//
#include <hip/hip_runtime.h>

// Problem constants (from reference setup_inputs): B=128, Q=500, C=80, T=64
#define BN 128
#define QN 500
#define CLS 80
#define TN 64
#define RPB 50                  // rows per cost block
#define CBI 10                  // cost blocks per image (500/50)

typedef unsigned long long ull;

// Monotonic float->uint map: a < b  <=>  fkey(a) < fkey(b); equal <=> equal
__device__ __forceinline__ unsigned fkey(float x) {
    unsigned u = __float_as_uint(x);
    return (u & 0x80000000u) ? ~u : (u | 0x80000000u);
}
__device__ __forceinline__ unsigned umin32(unsigned a, unsigned b) { return a < b ? a : b; }

// ---------------------------------------------------------------------------
// Kernel 1: cost matrix + per-block partial column minima.
// 1280 blocks (10 per image) x 256 threads; lane = column t, wave w handles
// rows q0+w, q0+w+4, ... Math is EXACTLY the round-4 formulation (expf,
// log1pf, logf, true divisions) -- fast-math variants perturb costs ~1e-4,
// which flips argmin ties and cascades through the sequential greedy
// (round-5 failure). Each block also emits partial[block][64] u64 colmin
// keys so assign never re-reads the 16.4 MB matrix for its init.
// ---------------------------------------------------------------------------
__global__ __launch_bounds__(256) void cost_kernel(
    const float* __restrict__ logits,   // [B,Q,C]
    const float* __restrict__ boxes,    // [B,Q,4]
    const int*   __restrict__ ids,      // [B,T]
    const float* __restrict__ tboxes,   // [B,T,4]
    const float* __restrict__ img,      // [B,4]
    float* __restrict__ Cout,           // [B,Q,T]
    ull* __restrict__ partial)          // [B*CBI, 64] or null
{
    const int b    = blockIdx.x / CBI;
    const int blk  = blockIdx.x % CBI;
    const int q0   = blk * RPB;
    const int wave = threadIdx.x >> 6;
    const int lane = threadIdx.x & 63;   // = column t

    // per-lane constants (same divisions as reference; hoisting is bit-exact)
    const float4 tb = *(const float4*)(tboxes + (size_t)(b * TN + lane) * 4);
    const float4 im = *(const float4*)(img + b * 4);
    const int    id = ids[b * TN + lane];
    const float tnx = tb.x / im.x, tny = tb.y / im.y;
    const float tnz = tb.z / im.z, tnw = tb.w / im.w;
    const float area_b = (tb.z - tb.x) * (tb.w - tb.y);

    ull colmin = ~0ull;
    for (int r = wave; r < RPB; r += 4) {
        const int q = q0 + r;
        const float4 pb = *(const float4*)(boxes + (size_t)(b * QN + q) * 4);
        const float x   = logits[(size_t)(b * QN + q) * CLS + id];

        // focal-style class cost (round-4 exact ops/order)
        float prob = 1.0f / (1.0f + expf(-x));
        float neg  = 0.75f * (prob * prob) * (-log1pf(1e-8f - prob));
        float pos  = 0.25f * ((1.0f - prob) * (1.0f - prob)) * (-logf(prob + 1e-8f));
        float cls  = pos - neg;

        // L1 on normalized boxes (true divisions, round-4 exact)
        float l1 = fabsf(pb.x / im.x - tnx) + fabsf(pb.y / im.y - tny)
                 + fabsf(pb.z / im.z - tnz) + fabsf(pb.w / im.w - tnw);

        // GIoU on pixel boxes (round-4 exact)
        float area_a = (pb.z - pb.x) * (pb.w - pb.y);
        float ltx = fmaxf(pb.x, tb.x), lty = fmaxf(pb.y, tb.y);
        float rbx = fminf(pb.z, tb.z), rby = fminf(pb.w, tb.w);
        float iw = fmaxf(rbx - ltx, 0.0f), ih = fmaxf(rby - lty, 0.0f);
        float inter = iw * ih;
        float uni   = area_a + area_b - inter;
        float iou   = inter / uni;
        float ex1 = fminf(pb.x, tb.x), ey1 = fminf(pb.y, tb.y);
        float ex2 = fmaxf(pb.z, tb.z), ey2 = fmaxf(pb.w, tb.w);
        float ew = fmaxf(ex2 - ex1, 0.0f), eh = fmaxf(ey2 - ey1, 0.0f);
        float enc = ew * eh;
        float giou = iou - (enc - uni) / enc;

        float cost = 5.0f * l1 + 2.0f * cls + 2.0f * (-giou);
        Cout[(size_t)(b * QN + q) * TN + lane] = cost;

        ull key = ((ull)fkey(cost) << 32) | (unsigned)(q * TN + lane);
        if (key < colmin) colmin = key;
    }

    if (partial) {
        __shared__ ull pk[4][TN];
        pk[wave][lane] = colmin;
        __syncthreads();
        if (wave == 0) {
            ull k = pk[0][lane];
            ull o = pk[1][lane]; if (o < k) k = o;
            o = pk[2][lane]; if (o < k) k = o;
            o = pk[3][lane]; if (o < k) k = o;
            partial[(size_t)blockIdx.x * TN + lane] = k;
        }
    }
}

// ---------------------------------------------------------------------------
// Kernel 2: greedy assignment, column-state. Lane j of wave 0 holds colmin[j]
// as u64 key (fkey<<32 | flat). Init from the 640KB partial table (coalesced)
// or fallback direct scan. Hot loop: 32-bit VALUE radix-4 butterfly (3 steps
// x 3 independent shuffles) + ballot/shfl index resolve; exact u64 min-flat
// path on multi-candidate ties (== reference raveled-argmin tie-break).
// Rescans (expected ~4.4 total per image) are cooperative 64-lane column
// scans with u64 butterfly. No barriers/LDS in the hot loop.
// ---------------------------------------------------------------------------
__global__ __launch_bounds__(512, 1) void assign_kernel(
    const float* __restrict__ Cmat,     // [B,Q,T]
    const ull* __restrict__ partial,    // [B*CBI,64] or null
    const int use_table,
    float* __restrict__ out_rows,       // [B,T] (as f32 values)
    float* __restrict__ out_cols)       // [B,T]
{
    const int b    = blockIdx.x;
    const int tid  = threadIdx.x;
    const int wave = tid >> 6;
    const int lane = tid & 63;
    const float* Cb = Cmat + (size_t)b * QN * TN;

    __shared__ ull wavecol[8][TN];

    if (use_table) {
        ull k = partial[(size_t)(b * CBI + wave) * TN + lane];
        if (wave < 2) {
            ull o = partial[(size_t)(b * CBI + 8 + wave) * TN + lane];
            if (o < k) k = o;
        }
        wavecol[wave][lane] = k;
    } else {
        // fallback: fixed trip count -> unrolled, loads pipelined
        const int rbeg = wave * 63;
        ull k = ~0ull;
        #pragma unroll
        for (int rr = 0; rr < 63; ++rr) {
            const int r = rbeg + rr;   // r <= 503: still inside d_out buffer
            float v = Cb[(size_t)r * TN + lane];
            ull kk = ((ull)fkey(v) << 32) | (unsigned)(r * TN + lane);
            if (r < QN && kk < k) k = kk;
        }
        wavecol[wave][lane] = k;
    }
    __syncthreads();
    if (wave != 0) return;              // hot loop is single-wave

    ull mykey = wavecol[0][lane];
    #pragma unroll
    for (int w = 1; w < 8; ++w) { ull o = wavecol[w][lane]; if (o < mykey) mykey = o; }

    // row-dead bitmask (wave-uniform values, static indices); rows 500..511
    // (rescan over-range) pre-marked dead.
    ull rowdead[8];
    #pragma unroll
    for (int w = 0; w < 8; ++w) rowdead[w] = 0ull;
    rowdead[7] = 0xFFF0000000000000ull;

    int my_i = 0, my_j = 0;             // lane t captures iteration t's result

    for (int t = 0; t < TN; ++t) {
        // --- global min VALUE: radix-4 butterfly on high 32 bits
        unsigned v = (unsigned)(mykey >> 32);
        unsigned a0 = __shfl_xor(v, 1), a1 = __shfl_xor(v, 2), a2 = __shfl_xor(v, 3);
        v = umin32(umin32(v, a0), umin32(a1, a2));
        a0 = __shfl_xor(v, 4); a1 = __shfl_xor(v, 8); a2 = __shfl_xor(v, 12);
        v = umin32(umin32(v, a0), umin32(a1, a2));
        a0 = __shfl_xor(v, 16); a1 = __shfl_xor(v, 32); a2 = __shfl_xor(v, 48);
        v = umin32(umin32(v, a0), umin32(a1, a2));

        // --- index resolve: unique candidate (common) = 1 shfl; ties ->
        // exact min-flat butterfly (matches raveled-argmin tie-break)
        const bool cand = ((unsigned)(mykey >> 32) == v);
        const ull cm = __ballot(cand);
        unsigned flat;
        if (__popcll(cm) == 1) {
            flat = __shfl((unsigned)mykey, (int)(__ffsll((long long)cm) - 1));
        } else {
            unsigned f = cand ? (unsigned)mykey : 0xFFFFFFFFu;
            a0 = __shfl_xor(f, 1); a1 = __shfl_xor(f, 2); a2 = __shfl_xor(f, 3);
            f = umin32(umin32(f, a0), umin32(a1, a2));
            a0 = __shfl_xor(f, 4); a1 = __shfl_xor(f, 8); a2 = __shfl_xor(f, 12);
            f = umin32(umin32(f, a0), umin32(a1, a2));
            a0 = __shfl_xor(f, 16); a1 = __shfl_xor(f, 32); a2 = __shfl_xor(f, 48);
            f = umin32(umin32(f, a0), umin32(a1, a2));
            flat = f;
        }
        flat = __builtin_amdgcn_readfirstlane(flat);
        const int i = (int)(flat >> 6);
        const int j = (int)(flat & 63u);
        if (lane == t) { my_i = i; my_j = j; }

        // retire winning column / row
        if (lane == j) mykey = ~0ull;
        #pragma unroll
        for (int w = 0; w < 8; ++w)
            if ((i >> 6) == w) rowdead[w] |= (1ull << (i & 63));

        // columns whose stored argmin row just died: cooperative rescan.
        // Retired cols have flat=0xFFFFFFFF -> argrow 0x3FFFFFF != i.
        unsigned argrow = ((unsigned)mykey) >> 6;
        ull need = __ballot(argrow == (unsigned)i);
        while (need) {
            int src = (int)(__ffsll((long long)need) - 1);
            need &= need - 1;
            unsigned jr = __shfl((unsigned)mykey, src) & 63u;
            ull nb = ~0ull;
            #pragma unroll
            for (int k8 = 0; k8 < 8; ++k8) {
                int r = lane + (k8 << 6);          // rows 500..511 masked dead
                float vv = Cb[(size_t)r * TN + (int)jr];
                bool dead = (rowdead[k8] >> lane) & 1ull;
                ull kk = dead ? ~0ull
                              : (((ull)fkey(vv) << 32) | (unsigned)(r * TN + (int)jr));
                if (kk < nb) nb = kk;
            }
            #pragma unroll
            for (int off = 1; off < 64; off <<= 1) {
                ull o = __shfl_xor(nb, off);
                if (o < nb) nb = o;
            }
            if (lane == (int)jr) mykey = nb;
        }
    }

    // coalesced index write: lane t holds iteration t's (i,j)
    out_rows[b * TN + lane] = (float)my_i;
    out_cols[b * TN + lane] = (float)my_j;
}

extern "C" void kernel_launch(void* const* d_in, const int* in_sizes, int n_in,
                              void* d_out, int out_size, void* d_ws, size_t ws_size,
                              hipStream_t stream) {
    const float* logits = (const float*)d_in[0];   // [128,500,80]
    const float* boxes  = (const float*)d_in[1];   // [128,500,4]
    const int*   ids    = (const int*)d_in[2];     // [128,64]
    const float* tboxes = (const float*)d_in[3];   // [128,64,4]
    const float* img    = (const float*)d_in[4];   // [128,4]

    float* out  = (float*)d_out;
    float* Cmat = out;                              // 128*500*64 = 4,096,000
    float* rows = out + (size_t)BN * QN * TN;       // +8192
    float* cols = rows + BN * TN;                   // +8192

    const size_t table_bytes = (size_t)BN * CBI * TN * sizeof(ull);  // 640 KB
    const bool use_table = (ws_size >= table_bytes);                  // constant across calls
    ull* partial = use_table ? (ull*)d_ws : nullptr;

    cost_kernel<<<BN * CBI, 256, 0, stream>>>(logits, boxes, ids, tboxes, img, Cmat, partial);
    assign_kernel<<<BN, 512, 0, stream>>>(Cmat, partial, use_table ? 1 : 0, rows, cols);
}